// Round 1
// baseline (471.469 us; speedup 1.0000x reference)
//
#include <hip/hip_runtime.h>
#include <math.h>

#define N_CH 256

__device__ __forceinline__ float sigmoidf_(float v) {
    return 1.0f / (1.0f + expf(-v));
}

// One wave (64 lanes) per node: lane l loads float4 -> exactly 256 floats/row.
__global__ __launch_bounds__(256) void dots_kernel(
    const float* __restrict__ x,
    const float* __restrict__ Wmlp, const float* __restrict__ Wlin,
    const float* __restrict__ Wgcn,
    float* __restrict__ s2dot, float* __restrict__ s3lin, float* __restrict__ xw,
    int n_nodes)
{
    int wave = (int)((blockIdx.x * (unsigned)blockDim.x + threadIdx.x) >> 6);
    int lane = threadIdx.x & 63;
    if (wave >= n_nodes) return;

    const float4* xr = (const float4*)(x + (size_t)wave * N_CH);
    float4 v  = xr[lane];
    float4 wm = ((const float4*)Wmlp)[lane];
    float4 wl = ((const float4*)Wlin)[lane];
    float4 wg = ((const float4*)Wgcn)[lane];

    float d0 = v.x*wm.x + v.y*wm.y + v.z*wm.z + v.w*wm.w;
    float d1 = v.x*wl.x + v.y*wl.y + v.z*wl.z + v.w*wl.w;
    float d2 = v.x*wg.x + v.y*wg.y + v.z*wg.z + v.w*wg.w;

    #pragma unroll
    for (int off = 32; off; off >>= 1) {
        d0 += __shfl_down(d0, off, 64);
        d1 += __shfl_down(d1, off, 64);
        d2 += __shfl_down(d2, off, 64);
    }
    if (lane == 0) {
        s2dot[wave] = d0;
        s3lin[wave] = d1;
        xw[wave]    = d2;
    }
}

__global__ __launch_bounds__(256) void deg_kernel(
    const int* __restrict__ dst, int* __restrict__ deg, int n_edges)
{
    int i = blockIdx.x * blockDim.x + threadIdx.x;
    if (i < n_edges) atomicAdd(&deg[dst[i]], 1);
}

__global__ __launch_bounds__(256) void dinv_kernel(
    const int* __restrict__ deg, float* __restrict__ dinv, int n)
{
    int i = blockIdx.x * blockDim.x + threadIdx.x;
    if (i < n) dinv[i] = rsqrtf((float)deg[i] + 1.0f);  // GCN deg includes self-loop
}

__global__ __launch_bounds__(256) void edge_kernel(
    const int* __restrict__ ei, const float* __restrict__ dinv,
    const float* __restrict__ xw, float* __restrict__ gcn, int n_edges)
{
    int i = blockIdx.x * blockDim.x + threadIdx.x;
    if (i >= n_edges) return;
    int s = ei[i];
    int d = ei[n_edges + i];
    atomicAdd(&gcn[d], dinv[s] * dinv[d] * xw[s]);
}

__global__ __launch_bounds__(256) void final_kernel(
    const int* __restrict__ deg, const float* __restrict__ dinv,
    const float* __restrict__ s2dot, const float* __restrict__ s3lin,
    const float* __restrict__ xw, const float* __restrict__ gcn,
    const float* __restrict__ alpha, const float* __restrict__ beta,
    const float* __restrict__ Watt, const float* __restrict__ batt,
    float* __restrict__ out, int n)
{
    int i = blockIdx.x * blockDim.x + threadIdx.x;
    if (i >= n) return;

    float a = alpha[0], b = beta[0];
    float s1 = sigmoidf_(a * sqrtf((float)deg[i]) + b);
    float s2 = sigmoidf_(s2dot[i]);
    float dn = dinv[i];
    float g  = gcn[i] + dn * dn * xw[i];     // add self-loop message
    float s3 = sigmoidf_(g + s3lin[i]);

    float z0 = Watt[0]*s1 + Watt[1]*s2 + Watt[2]*s3 + batt[0];
    float z1 = Watt[3]*s1 + Watt[4]*s2 + Watt[5]*s3 + batt[1];
    float z2 = Watt[6]*s1 + Watt[7]*s2 + Watt[8]*s3 + batt[2];

    float m  = fmaxf(z0, fmaxf(z1, z2));
    float e0 = expf(z0 - m), e1 = expf(z1 - m), e2 = expf(z2 - m);
    float inv = 1.0f / (e0 + e1 + e2);
    out[i] = (e0 * s1 + e1 * s2 + e2 * s3) * inv;
}

extern "C" void kernel_launch(void* const* d_in, const int* in_sizes, int n_in,
                              void* d_out, int out_size, void* d_ws, size_t ws_size,
                              hipStream_t stream) {
    const float* x     = (const float*)d_in[0];
    const int*   ei    = (const int*)d_in[1];    // [2, E] int32 (harness converts ints)
    const float* alpha = (const float*)d_in[2];
    const float* beta  = (const float*)d_in[3];
    const float* Wmlp  = (const float*)d_in[4];
    const float* Wlin  = (const float*)d_in[5];
    const float* Wgcn  = (const float*)d_in[6];
    const float* Watt  = (const float*)d_in[7];
    const float* batt  = (const float*)d_in[8];
    float* out = (float*)d_out;

    int n_nodes = in_sizes[0] / N_CH;
    int n_edges = in_sizes[1] / 2;

    // Workspace layout (floats): s2dot | s3lin | xw | dinv | gcn | deg(int)
    float* ws    = (float*)d_ws;
    float* s2dot = ws;
    float* s3lin = ws + (size_t)n_nodes;
    float* xw    = ws + (size_t)2 * n_nodes;
    float* dinv  = ws + (size_t)3 * n_nodes;
    float* gcn   = ws + (size_t)4 * n_nodes;
    int*   deg   = (int*)(ws + (size_t)5 * n_nodes);

    // zero gcn + deg in one memset (adjacent)
    hipMemsetAsync(gcn, 0, (size_t)n_nodes * 2 * sizeof(float), stream);

    dots_kernel<<<(n_nodes * 64 + 255) / 256, 256, 0, stream>>>(
        x, Wmlp, Wlin, Wgcn, s2dot, s3lin, xw, n_nodes);

    deg_kernel<<<(n_edges + 255) / 256, 256, 0, stream>>>(ei + n_edges, deg, n_edges);

    dinv_kernel<<<(n_nodes + 255) / 256, 256, 0, stream>>>(deg, dinv, n_nodes);

    edge_kernel<<<(n_edges + 255) / 256, 256, 0, stream>>>(ei, dinv, xw, gcn, n_edges);

    final_kernel<<<(n_nodes + 255) / 256, 256, 0, stream>>>(
        deg, dinv, s2dot, s3lin, xw, gcn, alpha, beta, Watt, batt, out, n_nodes);
}

// Round 2
// 459.651 us; speedup vs baseline: 1.0257x; 1.0257x over previous
//
#include <hip/hip_runtime.h>
#include <math.h>

#define N_CH 256
#define R 8   // accumulator replicas (contention reduction)

__device__ __forceinline__ float sigmoidf_(float v) {
    return 1.0f / (1.0f + expf(-v));
}

// Fused kernel: blocks [0, degBlocks) build the replicated in-degree histogram
// (4 edges/thread, int4 loads); remaining blocks do per-node dot products
// (1 wave per node). The atomic-latency-bound deg work overlaps the
// HBM-read-bound dots work on the same CUs.
__global__ __launch_bounds__(256) void dots_deg_kernel(
    const float* __restrict__ x,
    const float* __restrict__ Wmlp, const float* __restrict__ Wlin,
    const float* __restrict__ Wgcn,
    const int* __restrict__ dst,
    float* __restrict__ s2dot, float* __restrict__ s3lin, float* __restrict__ xw,
    int* __restrict__ deg_rep,
    int n_nodes, int n_edges, int degBlocks)
{
    if ((int)blockIdx.x < degBlocks) {
        int t = blockIdx.x * blockDim.x + threadIdx.x;
        int rep = ((int)blockIdx.x ^ ((int)threadIdx.x >> 6)) & (R - 1);
        int* deg = deg_rep + (size_t)rep * n_nodes;
        int base = t * 4;
        if (base + 3 < n_edges) {
            int4 d4 = *(const int4*)(dst + base);
            atomicAdd(&deg[d4.x], 1);
            atomicAdd(&deg[d4.y], 1);
            atomicAdd(&deg[d4.z], 1);
            atomicAdd(&deg[d4.w], 1);
        } else {
            for (int e = base; e < n_edges; ++e) atomicAdd(&deg[dst[e]], 1);
        }
        return;
    }

    int wid  = ((int)blockIdx.x - degBlocks) * ((int)blockDim.x >> 6)
             + ((int)threadIdx.x >> 6);
    int lane = threadIdx.x & 63;
    if (wid >= n_nodes) return;

    const float4* xr = (const float4*)(x + (size_t)wid * N_CH);
    float4 v  = xr[lane];
    float4 wm = ((const float4*)Wmlp)[lane];
    float4 wl = ((const float4*)Wlin)[lane];
    float4 wg = ((const float4*)Wgcn)[lane];

    float d0 = v.x*wm.x + v.y*wm.y + v.z*wm.z + v.w*wm.w;
    float d1 = v.x*wl.x + v.y*wl.y + v.z*wl.z + v.w*wl.w;
    float d2 = v.x*wg.x + v.y*wg.y + v.z*wg.z + v.w*wg.w;

    #pragma unroll
    for (int off = 32; off; off >>= 1) {
        d0 += __shfl_down(d0, off, 64);
        d1 += __shfl_down(d1, off, 64);
        d2 += __shfl_down(d2, off, 64);
    }
    if (lane == 0) {
        s2dot[wid] = d0;
        s3lin[wid] = d1;
        xw[wid]    = d2;
    }
}

// Sum deg replicas -> degf (float, no self-loop), dinv = rsqrt(deg+1),
// sxw = dinv * xw (pre-multiplied source term for the edge pass).
__global__ __launch_bounds__(256) void dinv_kernel(
    const int* __restrict__ deg_rep, const float* __restrict__ xw,
    float* __restrict__ degf, float* __restrict__ dinv, float* __restrict__ sxw,
    int n_nodes)
{
    int i = blockIdx.x * blockDim.x + threadIdx.x;
    if (i >= n_nodes) return;
    int d = 0;
    #pragma unroll
    for (int r = 0; r < R; ++r) d += deg_rep[(size_t)r * n_nodes + i];
    degf[i] = (float)d;
    float di = rsqrtf((float)d + 1.0f);   // GCN degree includes self-loop
    dinv[i] = di;
    sxw[i]  = di * xw[i];
}

// 4 edges/thread; message = sxw[s] * dinv[d]; replicated accumulators.
__global__ __launch_bounds__(256) void edge_kernel(
    const int* __restrict__ src, const int* __restrict__ dst,
    const float* __restrict__ dinv, const float* __restrict__ sxw,
    float* __restrict__ gcn_rep, int n_nodes, int n_edges)
{
    int t = blockIdx.x * blockDim.x + threadIdx.x;
    int rep = ((int)blockIdx.x ^ ((int)threadIdx.x >> 6)) & (R - 1);
    float* gcn = gcn_rep + (size_t)rep * n_nodes;
    int base = t * 4;
    if (base + 3 < n_edges) {
        int4 s4 = *(const int4*)(src + base);
        int4 d4 = *(const int4*)(dst + base);
        atomicAdd(&gcn[d4.x], sxw[s4.x] * dinv[d4.x]);
        atomicAdd(&gcn[d4.y], sxw[s4.y] * dinv[d4.y]);
        atomicAdd(&gcn[d4.z], sxw[s4.z] * dinv[d4.z]);
        atomicAdd(&gcn[d4.w], sxw[s4.w] * dinv[d4.w]);
    } else {
        for (int e = base; e < n_edges; ++e) {
            int s = src[e], d = dst[e];
            atomicAdd(&gcn[d], sxw[s] * dinv[d]);
        }
    }
}

__global__ __launch_bounds__(256) void final_kernel(
    const float* __restrict__ degf, const float* __restrict__ dinv,
    const float* __restrict__ s2dot, const float* __restrict__ s3lin,
    const float* __restrict__ xw, const float* __restrict__ gcn_rep,
    const float* __restrict__ alpha, const float* __restrict__ beta,
    const float* __restrict__ Watt, const float* __restrict__ batt,
    float* __restrict__ out, int n_nodes)
{
    int i = blockIdx.x * blockDim.x + threadIdx.x;
    if (i >= n_nodes) return;

    float g = 0.0f;
    #pragma unroll
    for (int r = 0; r < R; ++r) g += gcn_rep[(size_t)r * n_nodes + i];

    float a = alpha[0], b = beta[0];
    float s1 = sigmoidf_(a * sqrtf(degf[i]) + b);
    float s2 = sigmoidf_(s2dot[i]);
    float dn = dinv[i];
    g += dn * dn * xw[i];                 // self-loop message
    float s3 = sigmoidf_(g + s3lin[i]);

    float z0 = Watt[0]*s1 + Watt[1]*s2 + Watt[2]*s3 + batt[0];
    float z1 = Watt[3]*s1 + Watt[4]*s2 + Watt[5]*s3 + batt[1];
    float z2 = Watt[6]*s1 + Watt[7]*s2 + Watt[8]*s3 + batt[2];

    float m  = fmaxf(z0, fmaxf(z1, z2));
    float e0 = expf(z0 - m), e1 = expf(z1 - m), e2 = expf(z2 - m);
    float inv = 1.0f / (e0 + e1 + e2);
    out[i] = (e0 * s1 + e1 * s2 + e2 * s3) * inv;
}

extern "C" void kernel_launch(void* const* d_in, const int* in_sizes, int n_in,
                              void* d_out, int out_size, void* d_ws, size_t ws_size,
                              hipStream_t stream) {
    const float* x     = (const float*)d_in[0];
    const int*   ei    = (const int*)d_in[1];
    const float* alpha = (const float*)d_in[2];
    const float* beta  = (const float*)d_in[3];
    const float* Wmlp  = (const float*)d_in[4];
    const float* Wlin  = (const float*)d_in[5];
    const float* Wgcn  = (const float*)d_in[6];
    const float* Watt  = (const float*)d_in[7];
    const float* batt  = (const float*)d_in[8];
    float* out = (float*)d_out;

    int n_nodes = in_sizes[0] / N_CH;
    int n_edges = in_sizes[1] / 2;
    const int* src = ei;
    const int* dst = ei + n_edges;

    // ws layout (floats): s2dot|s3lin|xw|dinv|sxw|degf | gcn_rep[R*n] | deg_rep[R*n](int)
    float* ws      = (float*)d_ws;
    float* s2dot   = ws;
    float* s3lin   = ws + (size_t)n_nodes;
    float* xw      = ws + (size_t)2 * n_nodes;
    float* dinv    = ws + (size_t)3 * n_nodes;
    float* sxw     = ws + (size_t)4 * n_nodes;
    float* degf    = ws + (size_t)5 * n_nodes;
    float* gcn_rep = ws + (size_t)6 * n_nodes;
    int*   deg_rep = (int*)(ws + (size_t)(6 + R) * n_nodes);

    // zero gcn_rep + deg_rep (adjacent) in one async memset
    hipMemsetAsync(gcn_rep, 0, (size_t)2 * R * n_nodes * sizeof(float), stream);

    int edgeThreads = (n_edges + 3) / 4;
    int degBlocks   = (edgeThreads + 255) / 256;
    int dotsBlocks  = (n_nodes + 3) / 4;          // 4 waves/block, 1 wave/node
    dots_deg_kernel<<<degBlocks + dotsBlocks, 256, 0, stream>>>(
        x, Wmlp, Wlin, Wgcn, dst, s2dot, s3lin, xw, deg_rep,
        n_nodes, n_edges, degBlocks);

    dinv_kernel<<<(n_nodes + 255) / 256, 256, 0, stream>>>(
        deg_rep, xw, degf, dinv, sxw, n_nodes);

    edge_kernel<<<degBlocks, 256, 0, stream>>>(
        src, dst, dinv, sxw, gcn_rep, n_nodes, n_edges);

    final_kernel<<<(n_nodes + 255) / 256, 256, 0, stream>>>(
        degf, dinv, s2dot, s3lin, xw, gcn_rep, alpha, beta, batt ? Watt : Watt, batt,
        out, n_nodes);
}

// Round 3
// 311.662 us; speedup vs baseline: 1.5128x; 1.4748x over previous
//
#include <hip/hip_runtime.h>
#include <math.h>

#define N_CH   256
#define BSHIFT 7              // nodes per bucket = 128
#define NPB    128            // nodes per bucket
#define NBMAX  1024           // max buckets (LDS sizing); actual NB = 782
#define EPB    32768          // edges per histogram/scatter block
#define NBLKMAX 128           // max edge blocks (scan1 width); actual 98

__device__ __forceinline__ float sigmoidf_(float v) {
    return 1.0f / (1.0f + expf(-v));
}

// ---------------- dots: one wave per node, 3 dot products --------------------
__global__ __launch_bounds__(256) void dots_kernel(
    const float* __restrict__ x,
    const float* __restrict__ Wmlp, const float* __restrict__ Wlin,
    const float* __restrict__ Wgcn,
    float* __restrict__ s2dot, float* __restrict__ s3lin, float* __restrict__ xw,
    int n_nodes)
{
    int wid  = (int)((blockIdx.x * (unsigned)blockDim.x + threadIdx.x) >> 6);
    int lane = threadIdx.x & 63;
    if (wid >= n_nodes) return;

    const float4* xr = (const float4*)(x + (size_t)wid * N_CH);
    float4 v  = xr[lane];
    float4 wm = ((const float4*)Wmlp)[lane];
    float4 wl = ((const float4*)Wlin)[lane];
    float4 wg = ((const float4*)Wgcn)[lane];

    float d0 = v.x*wm.x + v.y*wm.y + v.z*wm.z + v.w*wm.w;
    float d1 = v.x*wl.x + v.y*wl.y + v.z*wl.z + v.w*wl.w;
    float d2 = v.x*wg.x + v.y*wg.y + v.z*wg.z + v.w*wg.w;

    #pragma unroll
    for (int off = 32; off; off >>= 1) {
        d0 += __shfl_down(d0, off, 64);
        d1 += __shfl_down(d1, off, 64);
        d2 += __shfl_down(d2, off, 64);
    }
    if (lane == 0) { s2dot[wid] = d0; s3lin[wid] = d1; xw[wid] = d2; }
}

// ---------------- pass 1: per-block bucket histogram (LDS) -------------------
__global__ __launch_bounds__(256) void hist_kernel(
    const int* __restrict__ dst, int* __restrict__ H,
    int n_edges, int nb, int nblk)
{
    __shared__ int h[NBMAX];
    for (int i = threadIdx.x; i < nb; i += 256) h[i] = 0;
    __syncthreads();

    int start = blockIdx.x * EPB;
    #pragma unroll 4
    for (int k = 0; k < EPB / 1024; ++k) {
        int e = start + (k * 256 + (int)threadIdx.x) * 4;
        if (e < n_edges) {
            int4 d4 = *(const int4*)(dst + e);
            atomicAdd(&h[d4.x >> BSHIFT], 1);
            atomicAdd(&h[d4.y >> BSHIFT], 1);
            atomicAdd(&h[d4.z >> BSHIFT], 1);
            atomicAdd(&h[d4.w >> BSHIFT], 1);
        }
    }
    __syncthreads();
    for (int b = threadIdx.x; b < nb; b += 256)
        H[(size_t)b * nblk + blockIdx.x] = h[b];   // bucket-major
}

// ---------------- pass 2a: per-bucket exclusive scan over blocks -------------
__global__ __launch_bounds__(NBLKMAX) void scan1_kernel(
    const int* __restrict__ H, int* __restrict__ O, int* __restrict__ totals,
    int nblk)
{
    __shared__ int s[NBLKMAX];
    int b = blockIdx.x, t = threadIdx.x;
    int v = (t < nblk) ? H[(size_t)b * nblk + t] : 0;
    s[t] = v;
    __syncthreads();
    for (int off = 1; off < NBLKMAX; off <<= 1) {
        int xx = s[t];
        int yy = (t >= off) ? s[t - off] : 0;
        __syncthreads();
        s[t] = xx + yy;
        __syncthreads();
    }
    if (t < nblk) O[(size_t)b * nblk + t] = s[t] - v;   // exclusive
    if (t == NBLKMAX - 1) totals[b] = s[t];
}

// ---------------- pass 2b: exclusive scan over bucket totals -----------------
__global__ __launch_bounds__(NBMAX) void scan2_kernel(
    const int* __restrict__ totals, int* __restrict__ bs, int nb)
{
    __shared__ int s[NBMAX];
    int t = threadIdx.x;
    int v = (t < nb) ? totals[t] : 0;
    s[t] = v;
    __syncthreads();
    for (int off = 1; off < NBMAX; off <<= 1) {
        int xx = s[t];
        int yy = (t >= off) ? s[t - off] : 0;
        __syncthreads();
        s[t] = xx + yy;
        __syncthreads();
    }
    if (t < nb) bs[t] = s[t] - v;
    if (t == NBMAX - 1) bs[nb] = s[t];   // == n_edges
}

// ---------------- pass 3: scatter edges into bucketed order ------------------
// packed word: src (17 bits) | local_dst (7 bits) << 17
__global__ __launch_bounds__(256) void scatter_kernel(
    const int* __restrict__ src, const int* __restrict__ dst,
    const int* __restrict__ O, const int* __restrict__ bs,
    int* __restrict__ bpack, int n_edges, int nblk)
{
    __shared__ int cnt[NBMAX];
    for (int i = threadIdx.x; i < NBMAX; i += 256) cnt[i] = 0;
    __syncthreads();

    int blk = blockIdx.x;
    int start = blk * EPB;
    #pragma unroll 4
    for (int k = 0; k < EPB / 1024; ++k) {
        int e = start + (k * 256 + (int)threadIdx.x) * 4;
        if (e < n_edges) {
            int4 s4 = *(const int4*)(src + e);
            int4 d4 = *(const int4*)(dst + e);
            int dd[4] = {d4.x, d4.y, d4.z, d4.w};
            int ss[4] = {s4.x, s4.y, s4.z, s4.w};
            #pragma unroll
            for (int j = 0; j < 4; ++j) {
                int b = dd[j] >> BSHIFT;
                int r = atomicAdd(&cnt[b], 1);
                int pos = bs[b] + O[(size_t)b * nblk + blk] + r;
                bpack[pos] = ss[j] | ((dd[j] & (NPB - 1)) << 17);
            }
        }
    }
}

// ---------------- pass 4: per-bucket degree -> dinv, sxw ---------------------
__global__ __launch_bounds__(256) void degdinv_kernel(
    const int* __restrict__ bpack, const int* __restrict__ bs,
    const float* __restrict__ xw,
    float* __restrict__ degf, float* __restrict__ dinv, float* __restrict__ sxw,
    int n_nodes)
{
    __shared__ int cnt[NPB];
    int b = blockIdx.x, t = threadIdx.x;
    if (t < NPB) cnt[t] = 0;
    __syncthreads();
    int e0 = bs[b], e1 = bs[b + 1];
    for (int e = e0 + t; e < e1; e += 256)
        atomicAdd(&cnt[bpack[e] >> 17], 1);
    __syncthreads();
    int node0 = b << BSHIFT;
    if (t < NPB && node0 + t < n_nodes) {
        int i = node0 + t;
        float d = (float)cnt[t];
        degf[i] = d;
        float di = rsqrtf(d + 1.0f);   // GCN degree includes self-loop
        dinv[i] = di;
        sxw[i]  = di * xw[i];
    }
}

// ---------------- pass 5: per-bucket gather + fused epilogue -----------------
__global__ __launch_bounds__(256) void gather_final_kernel(
    const int* __restrict__ bpack, const int* __restrict__ bs,
    const float* __restrict__ sxw, const float* __restrict__ dinv,
    const float* __restrict__ degf, const float* __restrict__ s2dot,
    const float* __restrict__ s3lin, const float* __restrict__ xw,
    const float* __restrict__ alpha, const float* __restrict__ beta,
    const float* __restrict__ Watt, const float* __restrict__ batt,
    float* __restrict__ out, int n_nodes)
{
    __shared__ float acc[NPB];
    int b = blockIdx.x, t = threadIdx.x;
    if (t < NPB) acc[t] = 0.0f;
    __syncthreads();
    int e0 = bs[b], e1 = bs[b + 1];
    for (int e = e0 + t; e < e1; e += 256) {
        int p = bpack[e];
        atomicAdd(&acc[p >> 17], sxw[p & 0x1FFFF]);
    }
    __syncthreads();
    int node0 = b << BSHIFT;
    if (t < NPB && node0 + t < n_nodes) {
        int i = node0 + t;
        float dn = dinv[i];
        float g  = acc[t] * dn + dn * dn * xw[i];     // norm factored + self-loop
        float s1 = sigmoidf_(alpha[0] * sqrtf(degf[i]) + beta[0]);
        float s2 = sigmoidf_(s2dot[i]);
        float s3 = sigmoidf_(g + s3lin[i]);

        float z0 = Watt[0]*s1 + Watt[1]*s2 + Watt[2]*s3 + batt[0];
        float z1 = Watt[3]*s1 + Watt[4]*s2 + Watt[5]*s3 + batt[1];
        float z2 = Watt[6]*s1 + Watt[7]*s2 + Watt[8]*s3 + batt[2];

        float m  = fmaxf(z0, fmaxf(z1, z2));
        float e0f = expf(z0 - m), e1f = expf(z1 - m), e2f = expf(z2 - m);
        float inv = 1.0f / (e0f + e1f + e2f);
        out[i] = (e0f * s1 + e1f * s2 + e2f * s3) * inv;
    }
}

extern "C" void kernel_launch(void* const* d_in, const int* in_sizes, int n_in,
                              void* d_out, int out_size, void* d_ws, size_t ws_size,
                              hipStream_t stream) {
    const float* x     = (const float*)d_in[0];
    const int*   ei    = (const int*)d_in[1];
    const float* alpha = (const float*)d_in[2];
    const float* beta  = (const float*)d_in[3];
    const float* Wmlp  = (const float*)d_in[4];
    const float* Wlin  = (const float*)d_in[5];
    const float* Wgcn  = (const float*)d_in[6];
    const float* Watt  = (const float*)d_in[7];
    const float* batt  = (const float*)d_in[8];
    float* out = (float*)d_out;

    int n_nodes = in_sizes[0] / N_CH;
    int n_edges = in_sizes[1] / 2;
    const int* src = ei;
    const int* dst = ei + n_edges;

    int nb   = (n_nodes + NPB - 1) >> BSHIFT;       // 782
    int nblk = (n_edges + EPB - 1) / EPB;           // 98

    // workspace layout (ints/floats, regions padded to 1024 elems)
    size_t off = 0;
    int*   bpack  = (int*)d_ws;                     off += (size_t)(n_edges + 1024 & ~1023);
    off = ((size_t)n_edges + 1023) & ~(size_t)1023;
    int*   H      = (int*)d_ws + off;               off += (((size_t)nb * nblk + 1023) & ~(size_t)1023);
    int*   O      = (int*)d_ws + off;               off += (((size_t)nb * nblk + 1023) & ~(size_t)1023);
    int*   totals = (int*)d_ws + off;               off += 1024;
    int*   bs     = (int*)d_ws + off;               off += 1024;
    float* s2dot  = (float*)d_ws + off;             off += (((size_t)n_nodes + 1023) & ~(size_t)1023);
    float* s3lin  = (float*)d_ws + off;             off += (((size_t)n_nodes + 1023) & ~(size_t)1023);
    float* xw     = (float*)d_ws + off;             off += (((size_t)n_nodes + 1023) & ~(size_t)1023);
    float* degf   = (float*)d_ws + off;             off += (((size_t)n_nodes + 1023) & ~(size_t)1023);
    float* dinv   = (float*)d_ws + off;             off += (((size_t)n_nodes + 1023) & ~(size_t)1023);
    float* sxw    = (float*)d_ws + off;             off += (((size_t)n_nodes + 1023) & ~(size_t)1023);

    dots_kernel<<<(n_nodes + 3) / 4, 256, 0, stream>>>(
        x, Wmlp, Wlin, Wgcn, s2dot, s3lin, xw, n_nodes);

    hist_kernel<<<nblk, 256, 0, stream>>>(dst, H, n_edges, nb, nblk);

    scan1_kernel<<<nb, NBLKMAX, 0, stream>>>(H, O, totals, nblk);

    scan2_kernel<<<1, NBMAX, 0, stream>>>(totals, bs, nb);

    scatter_kernel<<<nblk, 256, 0, stream>>>(src, dst, O, bs, bpack, n_edges, nblk);

    degdinv_kernel<<<nb, 256, 0, stream>>>(bpack, bs, xw, degf, dinv, sxw, n_nodes);

    gather_final_kernel<<<nb, 256, 0, stream>>>(
        bpack, bs, sxw, dinv, degf, s2dot, s3lin, xw,
        alpha, beta, Watt, batt, out, n_nodes);
}

// Round 4
// 272.713 us; speedup vs baseline: 1.7288x; 1.1428x over previous
//
#include <hip/hip_runtime.h>
#include <math.h>

#define N_CH   256
#define BSHIFT 7              // nodes per bucket = 128
#define NPB    128
#define NBMAX  1024           // LDS sizing; actual nb = 782
#define EPB_H  16384          // edges per hist block (fused under dots)
#define EPB_S  4096           // edges per scatter block (occupancy!)

__device__ __forceinline__ float sigmoidf_(float v) {
    return 1.0f / (1.0f + expf(-v));
}

// ---- fused: blocks [0,histBlocks) build bucket totals; rest do node dots ----
__global__ __launch_bounds__(256) void dots_hist_kernel(
    const float* __restrict__ x,
    const float* __restrict__ Wmlp, const float* __restrict__ Wlin,
    const float* __restrict__ Wgcn, const int* __restrict__ dst,
    float* __restrict__ s2dot, float* __restrict__ s3lin, float* __restrict__ xw,
    int* __restrict__ totals,
    int n_nodes, int n_edges, int nb, int histBlocks)
{
    __shared__ int h[NBMAX];
    if ((int)blockIdx.x < histBlocks) {
        for (int i = threadIdx.x; i < nb; i += 256) h[i] = 0;
        __syncthreads();
        int start = blockIdx.x * EPB_H;
        #pragma unroll 4
        for (int k = 0; k < EPB_H / 1024; ++k) {
            int e = start + (k * 256 + (int)threadIdx.x) * 4;
            if (e + 3 < n_edges) {
                int4 d4 = *(const int4*)(dst + e);
                atomicAdd(&h[d4.x >> BSHIFT], 1);
                atomicAdd(&h[d4.y >> BSHIFT], 1);
                atomicAdd(&h[d4.z >> BSHIFT], 1);
                atomicAdd(&h[d4.w >> BSHIFT], 1);
            } else {
                for (int ee = e; ee < n_edges; ++ee)
                    atomicAdd(&h[dst[ee] >> BSHIFT], 1);
            }
        }
        __syncthreads();
        for (int b = threadIdx.x; b < nb; b += 256)
            if (h[b]) atomicAdd(&totals[b], h[b]);
        return;
    }

    int wid  = ((int)blockIdx.x - histBlocks) * 4 + ((int)threadIdx.x >> 6);
    int lane = threadIdx.x & 63;
    if (wid >= n_nodes) return;

    const float4* xr = (const float4*)(x + (size_t)wid * N_CH);
    float4 v  = xr[lane];
    float4 wm = ((const float4*)Wmlp)[lane];
    float4 wl = ((const float4*)Wlin)[lane];
    float4 wg = ((const float4*)Wgcn)[lane];

    float d0 = v.x*wm.x + v.y*wm.y + v.z*wm.z + v.w*wm.w;
    float d1 = v.x*wl.x + v.y*wl.y + v.z*wl.z + v.w*wl.w;
    float d2 = v.x*wg.x + v.y*wg.y + v.z*wg.z + v.w*wg.w;

    #pragma unroll
    for (int off = 32; off; off >>= 1) {
        d0 += __shfl_down(d0, off, 64);
        d1 += __shfl_down(d1, off, 64);
        d2 += __shfl_down(d2, off, 64);
    }
    if (lane == 0) { s2dot[wid] = d0; s3lin[wid] = d1; xw[wid] = d2; }
}

// ---- exclusive scan over bucket totals; also seeds the allocation cursor ----
__global__ __launch_bounds__(1024) void scan_kernel(
    const int* __restrict__ totals, int* __restrict__ bs,
    int* __restrict__ cursor, int nb)
{
    __shared__ int s[1024];
    int t = threadIdx.x;
    int v = (t < nb) ? totals[t] : 0;
    s[t] = v;
    __syncthreads();
    for (int off = 1; off < 1024; off <<= 1) {
        int a = s[t];
        int b = (t >= off) ? s[t - off] : 0;
        __syncthreads();
        s[t] = a + b;
        __syncthreads();
    }
    if (t < nb) { int e = s[t] - v; bs[t] = e; cursor[t] = e; }
    if (t == 1023) bs[nb] = s[1023];
}

// ---- scatter: LDS hist -> per-block range reservation -> rank & write -------
// packed word: src (17 bits) | local_dst (7 bits) << 17
__global__ __launch_bounds__(256) void scatter_kernel(
    const int* __restrict__ src, const int* __restrict__ dst,
    int* __restrict__ cursor, int* __restrict__ bpack,
    int n_edges, int nb)
{
    __shared__ int h[NBMAX];
    __shared__ int base[NBMAX];
    for (int i = threadIdx.x; i < nb; i += 256) h[i] = 0;
    __syncthreads();

    int start = blockIdx.x * EPB_S;
    #pragma unroll 4
    for (int k = 0; k < EPB_S / 1024; ++k) {
        int e = start + (k * 256 + (int)threadIdx.x) * 4;
        if (e + 3 < n_edges) {
            int4 d4 = *(const int4*)(dst + e);
            atomicAdd(&h[d4.x >> BSHIFT], 1);
            atomicAdd(&h[d4.y >> BSHIFT], 1);
            atomicAdd(&h[d4.z >> BSHIFT], 1);
            atomicAdd(&h[d4.w >> BSHIFT], 1);
        } else {
            for (int ee = e; ee < n_edges; ++ee)
                atomicAdd(&h[dst[ee] >> BSHIFT], 1);
        }
    }
    __syncthreads();
    for (int b = threadIdx.x; b < nb; b += 256) {
        int c = h[b];
        base[b] = c ? atomicAdd(&cursor[b], c) : 0;
        h[b] = 0;
    }
    __syncthreads();
    #pragma unroll 4
    for (int k = 0; k < EPB_S / 1024; ++k) {
        int e = start + (k * 256 + (int)threadIdx.x) * 4;
        if (e + 3 < n_edges) {
            int4 s4 = *(const int4*)(src + e);
            int4 d4 = *(const int4*)(dst + e);
            int ss[4] = {s4.x, s4.y, s4.z, s4.w};
            int dd[4] = {d4.x, d4.y, d4.z, d4.w};
            #pragma unroll
            for (int j = 0; j < 4; ++j) {
                int b = dd[j] >> BSHIFT;
                int r = atomicAdd(&h[b], 1);
                bpack[base[b] + r] = ss[j] | ((dd[j] & (NPB - 1)) << 17);
            }
        } else {
            for (int ee = e; ee < n_edges; ++ee) {
                int d = dst[ee];
                int b = d >> BSHIFT;
                int r = atomicAdd(&h[b], 1);
                bpack[base[b] + r] = src[ee] | ((d & (NPB - 1)) << 17);
            }
        }
    }
}

// ---- per-bucket degree -> degf, dinv, sxw -----------------------------------
__global__ __launch_bounds__(256) void degdinv_kernel(
    const int* __restrict__ bpack, const int* __restrict__ bs,
    const float* __restrict__ xw,
    float* __restrict__ degf, float* __restrict__ dinv, float* __restrict__ sxw,
    int n_nodes)
{
    __shared__ int cnt[NPB];
    int b = blockIdx.x, t = threadIdx.x;
    if (t < NPB) cnt[t] = 0;
    __syncthreads();
    int e0 = bs[b], e1 = bs[b + 1];
    for (int e = e0 + t; e < e1; e += 256)
        atomicAdd(&cnt[bpack[e] >> 17], 1);
    __syncthreads();
    int node0 = b << BSHIFT;
    if (t < NPB && node0 + t < n_nodes) {
        int i = node0 + t;
        float d = (float)cnt[t];
        degf[i] = d;
        float di = rsqrtf(d + 1.0f);   // GCN degree includes self-loop
        dinv[i] = di;
        sxw[i]  = di * xw[i];
    }
}

// ---- per-bucket gather + fused epilogue -------------------------------------
__global__ __launch_bounds__(256) void gather_final_kernel(
    const int* __restrict__ bpack, const int* __restrict__ bs,
    const float* __restrict__ sxw, const float* __restrict__ dinv,
    const float* __restrict__ degf, const float* __restrict__ s2dot,
    const float* __restrict__ s3lin, const float* __restrict__ xw,
    const float* __restrict__ alpha, const float* __restrict__ beta,
    const float* __restrict__ Watt, const float* __restrict__ batt,
    float* __restrict__ out, int n_nodes)
{
    __shared__ float acc[NPB];
    int b = blockIdx.x, t = threadIdx.x;
    if (t < NPB) acc[t] = 0.0f;
    __syncthreads();
    int e0 = bs[b], e1 = bs[b + 1];
    for (int e = e0 + t; e < e1; e += 256) {
        int p = bpack[e];
        atomicAdd(&acc[p >> 17], sxw[p & 0x1FFFF]);
    }
    __syncthreads();
    int node0 = b << BSHIFT;
    if (t < NPB && node0 + t < n_nodes) {
        int i = node0 + t;
        float dn = dinv[i];
        float g  = acc[t] * dn + dn * dn * xw[i];     // factored norm + self-loop
        float s1 = sigmoidf_(alpha[0] * sqrtf(degf[i]) + beta[0]);
        float s2 = sigmoidf_(s2dot[i]);
        float s3 = sigmoidf_(g + s3lin[i]);

        float z0 = Watt[0]*s1 + Watt[1]*s2 + Watt[2]*s3 + batt[0];
        float z1 = Watt[3]*s1 + Watt[4]*s2 + Watt[5]*s3 + batt[1];
        float z2 = Watt[6]*s1 + Watt[7]*s2 + Watt[8]*s3 + batt[2];

        float m  = fmaxf(z0, fmaxf(z1, z2));
        float e0f = expf(z0 - m), e1f = expf(z1 - m), e2f = expf(z2 - m);
        float inv = 1.0f / (e0f + e1f + e2f);
        out[i] = (e0f * s1 + e1f * s2 + e2f * s3) * inv;
    }
}

extern "C" void kernel_launch(void* const* d_in, const int* in_sizes, int n_in,
                              void* d_out, int out_size, void* d_ws, size_t ws_size,
                              hipStream_t stream) {
    const float* x     = (const float*)d_in[0];
    const int*   ei    = (const int*)d_in[1];
    const float* alpha = (const float*)d_in[2];
    const float* beta  = (const float*)d_in[3];
    const float* Wmlp  = (const float*)d_in[4];
    const float* Wlin  = (const float*)d_in[5];
    const float* Wgcn  = (const float*)d_in[6];
    const float* Watt  = (const float*)d_in[7];
    const float* batt  = (const float*)d_in[8];
    float* out = (float*)d_out;

    int n_nodes = in_sizes[0] / N_CH;
    int n_edges = in_sizes[1] / 2;
    const int* src = ei;
    const int* dst = ei + n_edges;

    int nb = (n_nodes + NPB - 1) >> BSHIFT;             // 782
    int histBlocks    = (n_edges + EPB_H - 1) / EPB_H;  // 196
    int scatterBlocks = (n_edges + EPB_S - 1) / EPB_S;  // 782

    // ws layout (int/float elements, 1024-aligned regions)
    size_t off = 0;
    int*   bpack  = (int*)d_ws;          off += (((size_t)n_edges + 1023) & ~(size_t)1023);
    int*   totals = (int*)d_ws + off;    off += 1024;
    int*   bs     = (int*)d_ws + off;    off += 1024;
    int*   cursor = (int*)d_ws + off;    off += 1024;
    float* s2dot  = (float*)d_ws + off;  off += (((size_t)n_nodes + 1023) & ~(size_t)1023);
    float* s3lin  = (float*)d_ws + off;  off += (((size_t)n_nodes + 1023) & ~(size_t)1023);
    float* xw     = (float*)d_ws + off;  off += (((size_t)n_nodes + 1023) & ~(size_t)1023);
    float* degf   = (float*)d_ws + off;  off += (((size_t)n_nodes + 1023) & ~(size_t)1023);
    float* dinv   = (float*)d_ws + off;  off += (((size_t)n_nodes + 1023) & ~(size_t)1023);
    float* sxw    = (float*)d_ws + off;  off += (((size_t)n_nodes + 1023) & ~(size_t)1023);

    hipMemsetAsync(totals, 0, 1024 * sizeof(int), stream);

    int dotsBlocks = (n_nodes + 3) / 4;
    dots_hist_kernel<<<histBlocks + dotsBlocks, 256, 0, stream>>>(
        x, Wmlp, Wlin, Wgcn, dst, s2dot, s3lin, xw, totals,
        n_nodes, n_edges, nb, histBlocks);

    scan_kernel<<<1, 1024, 0, stream>>>(totals, bs, cursor, nb);

    scatter_kernel<<<scatterBlocks, 256, 0, stream>>>(
        src, dst, cursor, bpack, n_edges, nb);

    degdinv_kernel<<<nb, 256, 0, stream>>>(bpack, bs, xw, degf, dinv, sxw, n_nodes);

    gather_final_kernel<<<nb, 256, 0, stream>>>(
        bpack, bs, sxw, dinv, degf, s2dot, s3lin, xw,
        alpha, beta, Watt, batt, out, n_nodes);
}

// Round 5
// 259.176 us; speedup vs baseline: 1.8191x; 1.0522x over previous
//
#include <hip/hip_runtime.h>
#include <math.h>

#define N_CH    256
#define BSHIFT  7              // fine bucket = 128 nodes
#define NPB     128
#define NBMAX   1024           // fine buckets LDS sizing; actual nb = 782
#define SBSHIFT 11             // super-bucket = 2048 nodes
#define SBN     2048
#define NSMAX   64             // actual ns = 49
#define EPB_H   16384          // edges per hist block (fused under dots)
#define EPB1    4096           // edges per coarse-scatter block
#define EPB2    4096           // edges per fine-scatter block

__device__ __forceinline__ float sigmoidf_(float v) {
    return 1.0f / (1.0f + expf(-v));
}

// ---- fused: blocks [0,histBlocks) build fine-bucket totals; rest do dots ----
__global__ __launch_bounds__(256) void dots_hist_kernel(
    const float* __restrict__ x,
    const float* __restrict__ Wmlp, const float* __restrict__ Wlin,
    const float* __restrict__ Wgcn, const int* __restrict__ dst,
    float* __restrict__ s2dot, float* __restrict__ s3lin, float* __restrict__ xw,
    int* __restrict__ totals,
    int n_nodes, int n_edges, int nb, int histBlocks)
{
    __shared__ int h[NBMAX];
    if ((int)blockIdx.x < histBlocks) {
        for (int i = threadIdx.x; i < nb; i += 256) h[i] = 0;
        __syncthreads();
        int start = blockIdx.x * EPB_H;
        #pragma unroll 4
        for (int k = 0; k < EPB_H / 1024; ++k) {
            int e = start + (k * 256 + (int)threadIdx.x) * 4;
            if (e + 3 < n_edges) {
                int4 d4 = *(const int4*)(dst + e);
                atomicAdd(&h[d4.x >> BSHIFT], 1);
                atomicAdd(&h[d4.y >> BSHIFT], 1);
                atomicAdd(&h[d4.z >> BSHIFT], 1);
                atomicAdd(&h[d4.w >> BSHIFT], 1);
            } else {
                for (int ee = e; ee < n_edges && ee >= 0; ++ee)
                    atomicAdd(&h[dst[ee] >> BSHIFT], 1);
            }
        }
        __syncthreads();
        for (int b = threadIdx.x; b < nb; b += 256)
            if (h[b]) atomicAdd(&totals[b], h[b]);
        return;
    }

    int wid  = ((int)blockIdx.x - histBlocks) * 4 + ((int)threadIdx.x >> 6);
    int lane = threadIdx.x & 63;
    if (wid >= n_nodes) return;

    const float4* xr = (const float4*)(x + (size_t)wid * N_CH);
    float4 v  = xr[lane];
    float4 wm = ((const float4*)Wmlp)[lane];
    float4 wl = ((const float4*)Wlin)[lane];
    float4 wg = ((const float4*)Wgcn)[lane];

    float d0 = v.x*wm.x + v.y*wm.y + v.z*wm.z + v.w*wm.w;
    float d1 = v.x*wl.x + v.y*wl.y + v.z*wl.z + v.w*wl.w;
    float d2 = v.x*wg.x + v.y*wg.y + v.z*wg.z + v.w*wg.w;

    #pragma unroll
    for (int off = 32; off; off >>= 1) {
        d0 += __shfl_down(d0, off, 64);
        d1 += __shfl_down(d1, off, 64);
        d2 += __shfl_down(d2, off, 64);
    }
    if (lane == 0) { s2dot[wid] = d0; s3lin[wid] = d1; xw[wid] = d2; }
}

// ---- scan fine totals -> bs (exclusive), seed fine+coarse cursors, sbs ------
__global__ __launch_bounds__(1024) void scan_kernel(
    const int* __restrict__ totals, int* __restrict__ bs,
    int* __restrict__ cursor2, int* __restrict__ sbs, int* __restrict__ cursor1,
    int nb, int ns, int n_edges)
{
    __shared__ int s[1024];
    int t = threadIdx.x;
    int v = (t < nb) ? totals[t] : 0;
    s[t] = v;
    __syncthreads();
    for (int off = 1; off < 1024; off <<= 1) {
        int a = s[t];
        int b = (t >= off) ? s[t - off] : 0;
        __syncthreads();
        s[t] = a + b;
        __syncthreads();
    }
    if (t < nb) { int e = s[t] - v; bs[t] = e; cursor2[t] = e; }
    if (t == 1023) bs[nb] = s[1023];
    __syncthreads();
    if (t < ns) {
        int f = t << 4;                 // 16 fine buckets per super-bucket
        if (f > nb) f = nb;
        int v2 = bs[f];
        sbs[t] = v2;
        cursor1[t] = v2;
    }
    if (t == 0) sbs[ns] = n_edges;
}

// ---- pass A: coarse scatter into 49 super-buckets (long runs, coalesced) ----
// cpack word: src (17 bits) | local11 (11 bits) << 17
__global__ __launch_bounds__(256) void scatter1_kernel(
    const int* __restrict__ src, const int* __restrict__ dst,
    int* __restrict__ cursor1, int* __restrict__ cpack,
    int n_edges, int ns)
{
    __shared__ int h[NSMAX];
    __shared__ int base[NSMAX];
    if (threadIdx.x < NSMAX) h[threadIdx.x] = 0;
    __syncthreads();

    int start = blockIdx.x * EPB1;
    #pragma unroll 4
    for (int k = 0; k < EPB1 / 1024; ++k) {
        int e = start + (k * 256 + (int)threadIdx.x) * 4;
        if (e + 3 < n_edges) {
            int4 d4 = *(const int4*)(dst + e);
            atomicAdd(&h[d4.x >> SBSHIFT], 1);
            atomicAdd(&h[d4.y >> SBSHIFT], 1);
            atomicAdd(&h[d4.z >> SBSHIFT], 1);
            atomicAdd(&h[d4.w >> SBSHIFT], 1);
        } else {
            for (int ee = e; ee < n_edges && ee >= 0; ++ee)
                atomicAdd(&h[dst[ee] >> SBSHIFT], 1);
        }
    }
    __syncthreads();
    if (threadIdx.x < (unsigned)ns) {
        int c = h[threadIdx.x];
        base[threadIdx.x] = c ? atomicAdd(&cursor1[threadIdx.x], c) : 0;
        h[threadIdx.x] = 0;
    }
    __syncthreads();
    #pragma unroll 4
    for (int k = 0; k < EPB1 / 1024; ++k) {
        int e = start + (k * 256 + (int)threadIdx.x) * 4;
        if (e + 3 < n_edges) {
            int4 s4 = *(const int4*)(src + e);
            int4 d4 = *(const int4*)(dst + e);
            int ss[4] = {s4.x, s4.y, s4.z, s4.w};
            int dd[4] = {d4.x, d4.y, d4.z, d4.w};
            #pragma unroll
            for (int j = 0; j < 4; ++j) {
                int sb = dd[j] >> SBSHIFT;
                int r = atomicAdd(&h[sb], 1);
                cpack[base[sb] + r] = ss[j] | ((dd[j] & (SBN - 1)) << 17);
            }
        } else {
            for (int ee = e; ee < n_edges && ee >= 0; ++ee) {
                int d = dst[ee];
                int sb = d >> SBSHIFT;
                int r = atomicAdd(&h[sb], 1);
                cpack[base[sb] + r] = src[ee] | ((d & (SBN - 1)) << 17);
            }
        }
    }
}

// ---- pass B: fine scatter within super-buckets -------------------------------
// bpack word: src (17 bits) | local7 (7 bits) << 17
__global__ __launch_bounds__(256) void scatter2_kernel(
    const int* __restrict__ cpack, const int* __restrict__ sbs,
    int* __restrict__ cursor2, int* __restrict__ bpack,
    int n_edges, int nb, int ns)
{
    __shared__ int sbs_l[NSMAX + 1];
    __shared__ int h[NBMAX];
    __shared__ int base[NBMAX];
    if (threadIdx.x <= (unsigned)ns) sbs_l[threadIdx.x] = sbs[threadIdx.x];
    for (int i = threadIdx.x; i < nb; i += 256) h[i] = 0;
    __syncthreads();

    int start = blockIdx.x * EPB2;

    // histogram over fine buckets
    #pragma unroll 4
    for (int k = 0; k < EPB2 / 1024; ++k) {
        int p0 = start + (k * 256 + (int)threadIdx.x) * 4;
        // super-bucket via binary search (positions are sorted by sb)
        int lo = 0, hi = ns;
        while (hi - lo > 1) { int mid = (lo + hi) >> 1; if (sbs_l[mid] <= p0) lo = mid; else hi = mid; }
        int sb = lo;
        if (p0 + 3 < n_edges) {
            int4 w4 = *(const int4*)(cpack + p0);
            int ww[4] = {w4.x, w4.y, w4.z, w4.w};
            #pragma unroll
            for (int j = 0; j < 4; ++j) {
                while (p0 + j >= sbs_l[sb + 1]) ++sb;
                int l11 = ww[j] >> 17;
                atomicAdd(&h[(sb << 4) + (l11 >> BSHIFT)], 1);
            }
        } else {
            for (int p = p0; p < n_edges && p >= 0; ++p) {
                while (p >= sbs_l[sb + 1]) ++sb;
                int l11 = cpack[p] >> 17;
                atomicAdd(&h[(sb << 4) + (l11 >> BSHIFT)], 1);
            }
        }
    }
    __syncthreads();
    for (int b = threadIdx.x; b < nb; b += 256) {
        int c = h[b];
        base[b] = c ? atomicAdd(&cursor2[b], c) : 0;
        h[b] = 0;
    }
    __syncthreads();
    // rank & write
    #pragma unroll 4
    for (int k = 0; k < EPB2 / 1024; ++k) {
        int p0 = start + (k * 256 + (int)threadIdx.x) * 4;
        int lo = 0, hi = ns;
        while (hi - lo > 1) { int mid = (lo + hi) >> 1; if (sbs_l[mid] <= p0) lo = mid; else hi = mid; }
        int sb = lo;
        if (p0 + 3 < n_edges) {
            int4 w4 = *(const int4*)(cpack + p0);
            int ww[4] = {w4.x, w4.y, w4.z, w4.w};
            #pragma unroll
            for (int j = 0; j < 4; ++j) {
                while (p0 + j >= sbs_l[sb + 1]) ++sb;
                int l11 = ww[j] >> 17;
                int fb  = (sb << 4) + (l11 >> BSHIFT);
                int r = atomicAdd(&h[fb], 1);
                bpack[base[fb] + r] = (ww[j] & 0x1FFFF) | ((l11 & (NPB - 1)) << 17);
            }
        } else {
            for (int p = p0; p < n_edges && p >= 0; ++p) {
                while (p >= sbs_l[sb + 1]) ++sb;
                int w = cpack[p];
                int l11 = w >> 17;
                int fb  = (sb << 4) + (l11 >> BSHIFT);
                int r = atomicAdd(&h[fb], 1);
                bpack[base[fb] + r] = (w & 0x1FFFF) | ((l11 & (NPB - 1)) << 17);
            }
        }
    }
}

// ---- per-bucket degree -> degf, dinv, sxw -----------------------------------
__global__ __launch_bounds__(256) void degdinv_kernel(
    const int* __restrict__ bpack, const int* __restrict__ bs,
    const float* __restrict__ xw,
    float* __restrict__ degf, float* __restrict__ dinv, float* __restrict__ sxw,
    int n_nodes)
{
    __shared__ int cnt[NPB];
    int b = blockIdx.x, t = threadIdx.x;
    if (t < NPB) cnt[t] = 0;
    __syncthreads();
    int e0 = bs[b], e1 = bs[b + 1];
    for (int e = e0 + t; e < e1; e += 256)
        atomicAdd(&cnt[bpack[e] >> 17], 1);
    __syncthreads();
    int node0 = b << BSHIFT;
    if (t < NPB && node0 + t < n_nodes) {
        int i = node0 + t;
        float d = (float)cnt[t];
        degf[i] = d;
        float di = rsqrtf(d + 1.0f);   // GCN degree includes self-loop
        dinv[i] = di;
        sxw[i]  = di * xw[i];
    }
}

// ---- per-bucket gather + fused epilogue -------------------------------------
__global__ __launch_bounds__(256) void gather_final_kernel(
    const int* __restrict__ bpack, const int* __restrict__ bs,
    const float* __restrict__ sxw, const float* __restrict__ dinv,
    const float* __restrict__ degf, const float* __restrict__ s2dot,
    const float* __restrict__ s3lin, const float* __restrict__ xw,
    const float* __restrict__ alpha, const float* __restrict__ beta,
    const float* __restrict__ Watt, const float* __restrict__ batt,
    float* __restrict__ out, int n_nodes)
{
    __shared__ float acc[NPB];
    int b = blockIdx.x, t = threadIdx.x;
    if (t < NPB) acc[t] = 0.0f;
    __syncthreads();
    int e0 = bs[b], e1 = bs[b + 1];
    for (int e = e0 + t; e < e1; e += 256) {
        int p = bpack[e];
        atomicAdd(&acc[p >> 17], sxw[p & 0x1FFFF]);
    }
    __syncthreads();
    int node0 = b << BSHIFT;
    if (t < NPB && node0 + t < n_nodes) {
        int i = node0 + t;
        float dn = dinv[i];
        float g  = acc[t] * dn + dn * dn * xw[i];     // factored norm + self-loop
        float s1 = sigmoidf_(alpha[0] * sqrtf(degf[i]) + beta[0]);
        float s2 = sigmoidf_(s2dot[i]);
        float s3 = sigmoidf_(g + s3lin[i]);

        float z0 = Watt[0]*s1 + Watt[1]*s2 + Watt[2]*s3 + batt[0];
        float z1 = Watt[3]*s1 + Watt[4]*s2 + Watt[5]*s3 + batt[1];
        float z2 = Watt[6]*s1 + Watt[7]*s2 + Watt[8]*s3 + batt[2];

        float m  = fmaxf(z0, fmaxf(z1, z2));
        float e0f = expf(z0 - m), e1f = expf(z1 - m), e2f = expf(z2 - m);
        float inv = 1.0f / (e0f + e1f + e2f);
        out[i] = (e0f * s1 + e1f * s2 + e2f * s3) * inv;
    }
}

extern "C" void kernel_launch(void* const* d_in, const int* in_sizes, int n_in,
                              void* d_out, int out_size, void* d_ws, size_t ws_size,
                              hipStream_t stream) {
    const float* x     = (const float*)d_in[0];
    const int*   ei    = (const int*)d_in[1];
    const float* alpha = (const float*)d_in[2];
    const float* beta  = (const float*)d_in[3];
    const float* Wmlp  = (const float*)d_in[4];
    const float* Wlin  = (const float*)d_in[5];
    const float* Wgcn  = (const float*)d_in[6];
    const float* Watt  = (const float*)d_in[7];
    const float* batt  = (const float*)d_in[8];
    float* out = (float*)d_out;

    int n_nodes = in_sizes[0] / N_CH;
    int n_edges = in_sizes[1] / 2;
    const int* src = ei;
    const int* dst = ei + n_edges;

    int nb = (n_nodes + NPB - 1) >> BSHIFT;             // 782
    int ns = (n_nodes + SBN - 1) >> SBSHIFT;            // 49
    int histBlocks = (n_edges + EPB_H - 1) / EPB_H;     // 196
    int blocks1    = (n_edges + EPB1 - 1) / EPB1;       // 782
    int blocks2    = (n_edges + EPB2 - 1) / EPB2;       // 782

    // ws layout (int/float elements, 1024-aligned regions)
    size_t off = 0;
    int*   cpack   = (int*)d_ws;          off += (((size_t)n_edges + 1023) & ~(size_t)1023);
    int*   bpack   = (int*)d_ws + off;    off += (((size_t)n_edges + 1023) & ~(size_t)1023);
    int*   totals  = (int*)d_ws + off;    off += 1024;
    int*   bs      = (int*)d_ws + off;    off += 1024;
    int*   cursor2 = (int*)d_ws + off;    off += 1024;
    int*   sbs     = (int*)d_ws + off;    off += 128;
    int*   cursor1 = (int*)d_ws + off;    off += 128;
    float* s2dot   = (float*)d_ws + off;  off += (((size_t)n_nodes + 1023) & ~(size_t)1023);
    float* s3lin   = (float*)d_ws + off;  off += (((size_t)n_nodes + 1023) & ~(size_t)1023);
    float* xw      = (float*)d_ws + off;  off += (((size_t)n_nodes + 1023) & ~(size_t)1023);
    float* degf    = (float*)d_ws + off;  off += (((size_t)n_nodes + 1023) & ~(size_t)1023);
    float* dinv    = (float*)d_ws + off;  off += (((size_t)n_nodes + 1023) & ~(size_t)1023);
    float* sxw     = (float*)d_ws + off;  off += (((size_t)n_nodes + 1023) & ~(size_t)1023);

    hipMemsetAsync(totals, 0, 1024 * sizeof(int), stream);

    int dotsBlocks = (n_nodes + 3) / 4;
    dots_hist_kernel<<<histBlocks + dotsBlocks, 256, 0, stream>>>(
        x, Wmlp, Wlin, Wgcn, dst, s2dot, s3lin, xw, totals,
        n_nodes, n_edges, nb, histBlocks);

    scan_kernel<<<1, 1024, 0, stream>>>(totals, bs, cursor2, sbs, cursor1,
                                        nb, ns, n_edges);

    scatter1_kernel<<<blocks1, 256, 0, stream>>>(src, dst, cursor1, cpack,
                                                 n_edges, ns);

    scatter2_kernel<<<blocks2, 256, 0, stream>>>(cpack, sbs, cursor2, bpack,
                                                 n_edges, nb, ns);

    degdinv_kernel<<<nb, 256, 0, stream>>>(bpack, bs, xw, degf, dinv, sxw, n_nodes);

    gather_final_kernel<<<nb, 256, 0, stream>>>(
        bpack, bs, sxw, dinv, degf, s2dot, s3lin, xw,
        alpha, beta, Watt, batt, out, n_nodes);
}

// Round 6
// 255.112 us; speedup vs baseline: 1.8481x; 1.0159x over previous
//
#include <hip/hip_runtime.h>
#include <math.h>

#define N_CH    256
#define SBSHIFT 11             // super-bucket = 2048 nodes
#define SBN     2048
#define NSMAX   64             // actual ns = 49
#define CH      4096           // edges per chunk
#define EPB_H   16384          // 4 chunks per hist block
#define NCHMAX  1024           // >= nch(782); chunk table entries <= nch+ns = 831

__device__ __forceinline__ float sigmoidf_(float v) {
    return 1.0f / (1.0f + expf(-v));
}

// ---- fused: blocks [0,histBlocks) build per-chunk coarse histograms;
// ---- remaining blocks do the three per-node dot products (1 wave/node) -----
__global__ __launch_bounds__(256) void dots_hist_kernel(
    const float* __restrict__ x,
    const float* __restrict__ Wmlp, const float* __restrict__ Wlin,
    const float* __restrict__ Wgcn, const int* __restrict__ dst,
    float* __restrict__ s2dot, float* __restrict__ s3lin, float* __restrict__ xw,
    int* __restrict__ H1,
    int n_nodes, int n_edges, int ns, int nch, int histBlocks)
{
    __shared__ int h1[4][NSMAX];
    if ((int)blockIdx.x < histBlocks) {
        for (int i = threadIdx.x; i < 4 * NSMAX; i += 256) ((int*)h1)[i] = 0;
        __syncthreads();
        int start = blockIdx.x * EPB_H;
        for (int k = 0; k < 4; ++k) {           // 4 chunks per block
            for (int m = 0; m < 4; ++m) {       // 1024 edges per pass
                int e = start + k * CH + (m * 256 + (int)threadIdx.x) * 4;
                if (e + 3 < n_edges) {
                    int4 d4 = *(const int4*)(dst + e);
                    atomicAdd(&h1[k][d4.x >> SBSHIFT], 1);
                    atomicAdd(&h1[k][d4.y >> SBSHIFT], 1);
                    atomicAdd(&h1[k][d4.z >> SBSHIFT], 1);
                    atomicAdd(&h1[k][d4.w >> SBSHIFT], 1);
                } else {
                    for (int ee = e; ee < n_edges && ee >= 0; ++ee)
                        atomicAdd(&h1[k][dst[ee] >> SBSHIFT], 1);
                }
            }
        }
        __syncthreads();
        // 256 threads = 4 chunks x 64 bins
        int k  = threadIdx.x >> 6;
        int sb = threadIdx.x & 63;
        int chunk = blockIdx.x * 4 + k;
        if (sb < ns && chunk < nch)
            H1[(size_t)sb * nch + chunk] = h1[k][sb];
        return;
    }

    int wid  = ((int)blockIdx.x - histBlocks) * 4 + ((int)threadIdx.x >> 6);
    int lane = threadIdx.x & 63;
    if (wid >= n_nodes) return;

    const float4* xr = (const float4*)(x + (size_t)wid * N_CH);
    float4 v  = xr[lane];
    float4 wm = ((const float4*)Wmlp)[lane];
    float4 wl = ((const float4*)Wlin)[lane];
    float4 wg = ((const float4*)Wgcn)[lane];

    float d0 = v.x*wm.x + v.y*wm.y + v.z*wm.z + v.w*wm.w;
    float d1 = v.x*wl.x + v.y*wl.y + v.z*wl.z + v.w*wl.w;
    float d2 = v.x*wg.x + v.y*wg.y + v.z*wg.z + v.w*wg.w;

    #pragma unroll
    for (int off = 32; off; off >>= 1) {
        d0 += __shfl_down(d0, off, 64);
        d1 += __shfl_down(d1, off, 64);
        d2 += __shfl_down(d2, off, 64);
    }
    if (lane == 0) { s2dot[wid] = d0; s3lin[wid] = d1; xw[wid] = d2; }
}

// ---- scanA: per super-bucket, exclusive scan of its chunk counts ------------
__global__ __launch_bounds__(1024) void scanA_kernel(
    const int* __restrict__ H1, int* __restrict__ O, int* __restrict__ sbT,
    int nch)
{
    __shared__ int s[1024];
    int sb = blockIdx.x, t = threadIdx.x;
    int v = (t < nch) ? H1[(size_t)sb * nch + t] : 0;
    s[t] = v;
    __syncthreads();
    for (int off = 1; off < 1024; off <<= 1) {
        int a = s[t];
        int b = (t >= off) ? s[t - off] : 0;
        __syncthreads();
        s[t] = a + b;
        __syncthreads();
    }
    if (t < nch) O[(size_t)sb * nch + t] = s[t] - v;
    if (t == 1023) sbT[sb] = s[1023];
}

// ---- scanB: super-bucket offsets + chunk table ------------------------------
__global__ __launch_bounds__(256) void scanB_kernel(
    const int* __restrict__ sbT,
    int* __restrict__ sbs, int* __restrict__ cstart,
    int* __restrict__ chunkBase, int* __restrict__ chunkLen,
    int ns)
{
    __shared__ int sbsL[NSMAX + 1], nchL[NSMAX], cstL[NSMAX + 1];
    int t = threadIdx.x;
    if (t == 0) {
        int run = 0;
        for (int i = 0; i < ns; ++i) { sbsL[i] = run; run += sbT[i]; }
        sbsL[ns] = run;
        int c = 0;
        for (int i = 0; i < ns; ++i) {
            cstL[i] = c;
            int len = sbsL[i + 1] - sbsL[i];
            nchL[i] = (len + CH - 1) / CH;
            c += nchL[i];
        }
        cstL[ns] = c;
    }
    __syncthreads();
    if (t <= ns) { sbs[t] = sbsL[t]; cstart[t] = cstL[t]; }
    for (int i = t; i < NCHMAX; i += 256) chunkLen[i] = 0;
    __syncthreads();
    for (int sb = 0; sb < ns; ++sb) {
        int n = nchL[sb], base = sbsL[sb], cs = cstL[sb];
        int len = sbsL[sb + 1] - sbsL[sb];
        for (int i = t; i < n; i += 256) {
            chunkBase[cs + i] = base + i * CH;
            chunkLen[cs + i]  = min(CH, len - i * CH);
        }
    }
}

// ---- scatter1: single pass, precomputed slots, no cursor atomics ------------
// cpack word: src (17 bits) | local11 (11 bits) << 17
__global__ __launch_bounds__(256) void scatter1_kernel(
    const int* __restrict__ src, const int* __restrict__ dst,
    const int* __restrict__ sbs, const int* __restrict__ O,
    int* __restrict__ cpack, int n_edges, int ns, int nch)
{
    __shared__ int pos0[NSMAX];
    __shared__ int h[NSMAX];
    int c = blockIdx.x;
    if (threadIdx.x < NSMAX) {
        h[threadIdx.x] = 0;
        if (threadIdx.x < (unsigned)ns)
            pos0[threadIdx.x] = sbs[threadIdx.x] + O[(size_t)threadIdx.x * nch + c];
    }
    __syncthreads();
    int start = c * CH;
    for (int m = 0; m < 4; ++m) {
        int e = start + (m * 256 + (int)threadIdx.x) * 4;
        if (e + 3 < n_edges) {
            int4 s4 = *(const int4*)(src + e);
            int4 d4 = *(const int4*)(dst + e);
            int ss[4] = {s4.x, s4.y, s4.z, s4.w};
            int dd[4] = {d4.x, d4.y, d4.z, d4.w};
            #pragma unroll
            for (int j = 0; j < 4; ++j) {
                int sb = dd[j] >> SBSHIFT;
                int r = atomicAdd(&h[sb], 1);
                cpack[pos0[sb] + r] = ss[j] | ((dd[j] & (SBN - 1)) << 17);
            }
        } else {
            for (int ee = e; ee < n_edges && ee >= 0; ++ee) {
                int d = dst[ee];
                int sb = d >> SBSHIFT;
                int r = atomicAdd(&h[sb], 1);
                cpack[pos0[sb] + r] = src[ee] | ((d & (SBN - 1)) << 17);
            }
        }
    }
}

// ---- chunkDeg: per-chunk node counts into dense partial rows ----------------
__global__ __launch_bounds__(256) void chunkDeg_kernel(
    const int* __restrict__ cpack, const int* __restrict__ chunkBase,
    const int* __restrict__ chunkLen, int* __restrict__ partialD)
{
    __shared__ int cnt[SBN];
    int c = blockIdx.x;
    int len = chunkLen[c];
    for (int i = threadIdx.x; i < SBN; i += 256) cnt[i] = 0;
    __syncthreads();
    if (len > 0) {
        int base = chunkBase[c];
        for (int e = threadIdx.x; e < len; e += 256)
            atomicAdd(&cnt[cpack[base + e] >> 17], 1);
    }
    __syncthreads();
    if (len > 0) {
        int* row = partialD + (size_t)c * SBN;
        for (int i = threadIdx.x; i < SBN; i += 256) row[i] = cnt[i];
    }
}

// ---- reduceDeg: per-node degree -> degf, dinv, sxw --------------------------
__global__ __launch_bounds__(256) void reduceDeg_kernel(
    const int* __restrict__ partialD, const int* __restrict__ cstart,
    const float* __restrict__ xw,
    float* __restrict__ degf, float* __restrict__ dinv, float* __restrict__ sxw,
    int n_nodes)
{
    int i = blockIdx.x * 256 + threadIdx.x;
    if (i >= n_nodes) return;
    int sb = i >> SBSHIFT, li = i & (SBN - 1);
    int c0 = cstart[sb], c1 = cstart[sb + 1];
    int d = 0;
    for (int c = c0; c < c1; ++c) d += partialD[(size_t)c * SBN + li];
    float df = (float)d;
    degf[i] = df;
    float di = rsqrtf(df + 1.0f);        // GCN degree includes self-loop
    dinv[i] = di;
    sxw[i]  = di * xw[i];
}

// ---- chunkAcc: per-chunk sum of sxw[src] into dense partial rows ------------
__global__ __launch_bounds__(256) void chunkAcc_kernel(
    const int* __restrict__ cpack, const int* __restrict__ chunkBase,
    const int* __restrict__ chunkLen, const float* __restrict__ sxw,
    float* __restrict__ partialF)
{
    __shared__ float facc[SBN];
    int c = blockIdx.x;
    int len = chunkLen[c];
    for (int i = threadIdx.x; i < SBN; i += 256) facc[i] = 0.0f;
    __syncthreads();
    if (len > 0) {
        int base = chunkBase[c];
        for (int e = threadIdx.x; e < len; e += 256) {
            int w = cpack[base + e];
            atomicAdd(&facc[w >> 17], sxw[w & 0x1FFFF]);
        }
    }
    __syncthreads();
    if (len > 0) {
        float* row = partialF + (size_t)c * SBN;
        for (int i = threadIdx.x; i < SBN; i += 256) row[i] = facc[i];
    }
}

// ---- reduceFinal: per-node accumulate + fused epilogue ----------------------
__global__ __launch_bounds__(256) void reduceFinal_kernel(
    const float* __restrict__ partialF, const int* __restrict__ cstart,
    const float* __restrict__ degf, const float* __restrict__ dinv,
    const float* __restrict__ xw, const float* __restrict__ s2dot,
    const float* __restrict__ s3lin,
    const float* __restrict__ alpha, const float* __restrict__ beta,
    const float* __restrict__ Watt, const float* __restrict__ batt,
    float* __restrict__ out, int n_nodes)
{
    int i = blockIdx.x * 256 + threadIdx.x;
    if (i >= n_nodes) return;
    int sb = i >> SBSHIFT, li = i & (SBN - 1);
    int c0 = cstart[sb], c1 = cstart[sb + 1];
    float acc = 0.0f;
    for (int c = c0; c < c1; ++c) acc += partialF[(size_t)c * SBN + li];

    float dn = dinv[i];
    float g  = acc * dn + dn * dn * xw[i];     // factored norm + self-loop
    float s1 = sigmoidf_(alpha[0] * sqrtf(degf[i]) + beta[0]);
    float s2 = sigmoidf_(s2dot[i]);
    float s3 = sigmoidf_(g + s3lin[i]);

    float z0 = Watt[0]*s1 + Watt[1]*s2 + Watt[2]*s3 + batt[0];
    float z1 = Watt[3]*s1 + Watt[4]*s2 + Watt[5]*s3 + batt[1];
    float z2 = Watt[6]*s1 + Watt[7]*s2 + Watt[8]*s3 + batt[2];

    float m  = fmaxf(z0, fmaxf(z1, z2));
    float e0 = expf(z0 - m), e1 = expf(z1 - m), e2 = expf(z2 - m);
    float inv = 1.0f / (e0 + e1 + e2);
    out[i] = (e0 * s1 + e1 * s2 + e2 * s3) * inv;
}

extern "C" void kernel_launch(void* const* d_in, const int* in_sizes, int n_in,
                              void* d_out, int out_size, void* d_ws, size_t ws_size,
                              hipStream_t stream) {
    const float* x     = (const float*)d_in[0];
    const int*   ei    = (const int*)d_in[1];
    const float* alpha = (const float*)d_in[2];
    const float* beta  = (const float*)d_in[3];
    const float* Wmlp  = (const float*)d_in[4];
    const float* Wlin  = (const float*)d_in[5];
    const float* Wgcn  = (const float*)d_in[6];
    const float* Watt  = (const float*)d_in[7];
    const float* batt  = (const float*)d_in[8];
    float* out = (float*)d_out;

    int n_nodes = in_sizes[0] / N_CH;
    int n_edges = in_sizes[1] / 2;
    const int* src = ei;
    const int* dst = ei + n_edges;

    int ns  = (n_nodes + SBN - 1) >> SBSHIFT;        // 49
    int nch = (n_edges + CH - 1) / CH;               // 782
    int histBlocks = (n_edges + EPB_H - 1) / EPB_H;  // 196
    int maxChunks  = nch + ns;                       // 831 (chunk-table bound)

    // ws layout (4-byte elements, 1024-aligned regions)
    size_t off = 0;
    int*   cpack     = (int*)d_ws;          off += (((size_t)n_edges + 1023) & ~(size_t)1023);
    int*   H1        = (int*)d_ws + off;    off += (((size_t)ns * nch + 1023) & ~(size_t)1023);
    int*   O         = (int*)d_ws + off;    off += (((size_t)ns * nch + 1023) & ~(size_t)1023);
    int*   sbT       = (int*)d_ws + off;    off += 128;
    int*   sbs       = (int*)d_ws + off;    off += 128;
    int*   cstart    = (int*)d_ws + off;    off += 128;
    int*   chunkBase = (int*)d_ws + off;    off += NCHMAX;
    int*   chunkLen  = (int*)d_ws + off;    off += NCHMAX;
    int*   partialD  = (int*)d_ws + off;    off += (size_t)maxChunks * SBN;
    float* partialF  = (float*)d_ws + off;  off += (size_t)maxChunks * SBN;
    float* s2dot     = (float*)d_ws + off;  off += (((size_t)n_nodes + 1023) & ~(size_t)1023);
    float* s3lin     = (float*)d_ws + off;  off += (((size_t)n_nodes + 1023) & ~(size_t)1023);
    float* xw        = (float*)d_ws + off;  off += (((size_t)n_nodes + 1023) & ~(size_t)1023);
    float* degf      = (float*)d_ws + off;  off += (((size_t)n_nodes + 1023) & ~(size_t)1023);
    float* dinv      = (float*)d_ws + off;  off += (((size_t)n_nodes + 1023) & ~(size_t)1023);
    float* sxw       = (float*)d_ws + off;  off += (((size_t)n_nodes + 1023) & ~(size_t)1023);

    int dotsBlocks = (n_nodes + 3) / 4;
    dots_hist_kernel<<<histBlocks + dotsBlocks, 256, 0, stream>>>(
        x, Wmlp, Wlin, Wgcn, dst, s2dot, s3lin, xw, H1,
        n_nodes, n_edges, ns, nch, histBlocks);

    scanA_kernel<<<ns, 1024, 0, stream>>>(H1, O, sbT, nch);

    scanB_kernel<<<1, 256, 0, stream>>>(sbT, sbs, cstart, chunkBase, chunkLen, ns);

    scatter1_kernel<<<nch, 256, 0, stream>>>(src, dst, sbs, O, cpack,
                                             n_edges, ns, nch);

    chunkDeg_kernel<<<maxChunks, 256, 0, stream>>>(cpack, chunkBase, chunkLen,
                                                   partialD);

    reduceDeg_kernel<<<(n_nodes + 255) / 256, 256, 0, stream>>>(
        partialD, cstart, xw, degf, dinv, sxw, n_nodes);

    chunkAcc_kernel<<<maxChunks, 256, 0, stream>>>(cpack, chunkBase, chunkLen,
                                                   sxw, partialF);

    reduceFinal_kernel<<<(n_nodes + 255) / 256, 256, 0, stream>>>(
        partialF, cstart, degf, dinv, xw, s2dot, s3lin,
        alpha, beta, Watt, batt, out, n_nodes);
}

// Round 7
// 244.515 us; speedup vs baseline: 1.9282x; 1.0433x over previous
//
#include <hip/hip_runtime.h>
#include <math.h>

#define N_CH    256
#define SBSHIFT 11             // super-bucket = 2048 nodes
#define SBN     2048
#define NSMAX   64             // actual ns = 49
#define CH      4096           // edges per chunk (input chunks AND output chunks)

__device__ __forceinline__ float sigmoidf_(float v) {
    return 1.0f / (1.0f + expf(-v));
}

// Build the 49-entry prefix tables from sbT in-block (thread 0 -> LDS).
// sbsL[0..ns] = edge offsets of super-buckets; cstL[0..ns] = dense chunk ids.
__device__ __forceinline__ void build_tables(const int* sbT, int ns,
                                             int* sbsL, int* cstL) {
    if (threadIdx.x == 0) {
        int run = 0, c = 0;
        for (int i = 0; i < ns; ++i) {
            sbsL[i] = run;
            cstL[i] = c;
            int len = sbT[i];
            run += len;
            c += (len + CH - 1) / CH;
        }
        sbsL[ns] = run;
        cstL[ns] = c;
    }
}

// ---- K1 fused: blocks [0,nch) histogram one input chunk into 49 coarse bins;
// ---- remaining blocks: three per-node dot products (1 wave/node) ------------
__global__ __launch_bounds__(256) void dots_hist_kernel(
    const float* __restrict__ x,
    const float* __restrict__ Wmlp, const float* __restrict__ Wlin,
    const float* __restrict__ Wgcn, const int* __restrict__ dst,
    float* __restrict__ s2dot, float* __restrict__ s3lin, float* __restrict__ xw,
    int* __restrict__ H1,
    int n_nodes, int n_edges, int ns, int nch)
{
    __shared__ int h[NSMAX];
    if ((int)blockIdx.x < nch) {
        int c = blockIdx.x;
        if (threadIdx.x < NSMAX) h[threadIdx.x] = 0;
        __syncthreads();
        int start = c * CH;
        #pragma unroll
        for (int m = 0; m < 4; ++m) {
            int e = start + (m * 256 + (int)threadIdx.x) * 4;
            if (e + 3 < n_edges) {
                int4 d4 = *(const int4*)(dst + e);
                atomicAdd(&h[d4.x >> SBSHIFT], 1);
                atomicAdd(&h[d4.y >> SBSHIFT], 1);
                atomicAdd(&h[d4.z >> SBSHIFT], 1);
                atomicAdd(&h[d4.w >> SBSHIFT], 1);
            } else {
                for (int ee = e; ee < n_edges && ee >= 0; ++ee)
                    atomicAdd(&h[dst[ee] >> SBSHIFT], 1);
            }
        }
        __syncthreads();
        if (threadIdx.x < (unsigned)ns)
            H1[(size_t)threadIdx.x * nch + c] = h[threadIdx.x];
        return;
    }

    int wid  = ((int)blockIdx.x - nch) * 4 + ((int)threadIdx.x >> 6);
    int lane = threadIdx.x & 63;
    if (wid >= n_nodes) return;

    const float4* xr = (const float4*)(x + (size_t)wid * N_CH);
    float4 v  = xr[lane];
    float4 wm = ((const float4*)Wmlp)[lane];
    float4 wl = ((const float4*)Wlin)[lane];
    float4 wg = ((const float4*)Wgcn)[lane];

    float d0 = v.x*wm.x + v.y*wm.y + v.z*wm.z + v.w*wm.w;
    float d1 = v.x*wl.x + v.y*wl.y + v.z*wl.z + v.w*wl.w;
    float d2 = v.x*wg.x + v.y*wg.y + v.z*wg.z + v.w*wg.w;

    #pragma unroll
    for (int off = 32; off; off >>= 1) {
        d0 += __shfl_down(d0, off, 64);
        d1 += __shfl_down(d1, off, 64);
        d2 += __shfl_down(d2, off, 64);
    }
    if (lane == 0) { s2dot[wid] = d0; s3lin[wid] = d1; xw[wid] = d2; }
}

// ---- K2 scanA: per super-bucket exclusive scan of its input-chunk counts ----
__global__ __launch_bounds__(1024) void scanA_kernel(
    const int* __restrict__ H1, int* __restrict__ O, int* __restrict__ sbT,
    int nch)
{
    __shared__ int s[1024];
    int sb = blockIdx.x, t = threadIdx.x;
    int v = (t < nch) ? H1[(size_t)sb * nch + t] : 0;
    s[t] = v;
    __syncthreads();
    for (int off = 1; off < 1024; off <<= 1) {
        int a = s[t];
        int b = (t >= off) ? s[t - off] : 0;
        __syncthreads();
        s[t] = a + b;
        __syncthreads();
    }
    if (t < nch) O[(size_t)sb * nch + t] = s[t] - v;
    if (t == 1023) sbT[sb] = s[1023];
}

// ---- K3 scatter: LDS counting sort per 4096-edge chunk, coalesced flush -----
// cpack word: src (17 bits) | local11 (11 bits) << 17
__global__ __launch_bounds__(256) void scatter_kernel(
    const int* __restrict__ src, const int* __restrict__ dst,
    const int* __restrict__ sbT, const int* __restrict__ O,
    int* __restrict__ cpack, int n_edges, int ns, int nch)
{
    __shared__ int sbsL[NSMAX + 1], cstL[NSMAX + 1];
    __shared__ int pos0[NSMAX];        // global base for this block's segment
    __shared__ int lp[NSMAX + 1];      // local (in-chunk) exclusive prefix
    __shared__ int h[NSMAX];           // hist, then rank counters
    __shared__ int sorted[CH];         // 16 KB

    int c = blockIdx.x;
    build_tables(sbT, ns, sbsL, cstL);
    if (threadIdx.x < NSMAX) h[threadIdx.x] = 0;
    __syncthreads();
    if (threadIdx.x < (unsigned)ns)
        pos0[threadIdx.x] = sbsL[threadIdx.x] + O[(size_t)threadIdx.x * nch + c];

    int start = c * CH;
    int cnt = n_edges - start; if (cnt > CH) cnt = CH;

    // load edges into registers + LDS histogram
    int4 s4[4], d4[4];
    #pragma unroll
    for (int m = 0; m < 4; ++m) {
        int e = start + (m * 256 + (int)threadIdx.x) * 4;
        if (e + 3 < n_edges) {
            s4[m] = *(const int4*)(src + e);
            d4[m] = *(const int4*)(dst + e);
            atomicAdd(&h[d4[m].x >> SBSHIFT], 1);
            atomicAdd(&h[d4[m].y >> SBSHIFT], 1);
            atomicAdd(&h[d4[m].z >> SBSHIFT], 1);
            atomicAdd(&h[d4[m].w >> SBSHIFT], 1);
        } else {
            s4[m] = make_int4(-1, -1, -1, -1);
            int* sp = (int*)&s4[m]; int* dp = (int*)&d4[m];
            for (int j = 0; j < 4; ++j) {
                int ee = e + j;
                if (ee < n_edges && ee >= 0) {
                    sp[j] = src[ee]; dp[j] = dst[ee];
                    atomicAdd(&h[dp[j] >> SBSHIFT], 1);
                }
            }
        }
    }
    __syncthreads();
    // local exclusive prefix (thread 0, 49 entries) and reset h for ranking
    if (threadIdx.x == 0) {
        int run = 0;
        for (int i = 0; i < ns; ++i) { lp[i] = run; run += h[i]; }
        lp[ns] = run;
    }
    __syncthreads();
    if (threadIdx.x < NSMAX) h[threadIdx.x] = 0;
    __syncthreads();
    // rank into LDS at locally-sorted position
    #pragma unroll
    for (int m = 0; m < 4; ++m) {
        int* sp = (int*)&s4[m]; int* dp = (int*)&d4[m];
        #pragma unroll
        for (int j = 0; j < 4; ++j) {
            if (sp[j] >= 0) {
                int d = dp[j];
                int sb = d >> SBSHIFT;
                int r = atomicAdd(&h[sb], 1);
                sorted[lp[sb] + r] = sp[j] | ((d & (SBN - 1)) << 17);
            }
        }
    }
    __syncthreads();
    // coalesced flush: linear LDS position -> contiguous global segment
    for (int p = threadIdx.x; p < cnt; p += 256) {
        int lo = 0, hi = ns;
        while (hi - lo > 1) { int mid = (lo + hi) >> 1; if (lp[mid] <= p) lo = mid; else hi = mid; }
        cpack[pos0[lo] + (p - lp[lo])] = sorted[p];
    }
}

// ---- K4 chunkDeg: per output chunk, node counts -> dense partial row --------
__global__ __launch_bounds__(256) void chunkDeg_kernel(
    const int* __restrict__ cpack, const int* __restrict__ sbT,
    int* __restrict__ partialD, int ns)
{
    __shared__ int sbsL[NSMAX + 1], cstL[NSMAX + 1];
    __shared__ int cnt[SBN];
    build_tables(sbT, ns, sbsL, cstL);
    for (int i = threadIdx.x; i < SBN; i += 256) cnt[i] = 0;
    __syncthreads();
    int c = blockIdx.x;
    if (c >= cstL[ns]) return;
    // find sb: cstL[sb] <= c < cstL[sb+1]
    int lo = 0, hi = ns;
    while (hi - lo > 1) { int mid = (lo + hi) >> 1; if (cstL[mid] <= c) lo = mid; else hi = mid; }
    int sb = lo;
    int i0 = c - cstL[sb];
    int base = sbsL[sb] + i0 * CH;
    int len = sbsL[sb + 1] - base; if (len > CH) len = CH;

    #pragma unroll
    for (int m = 0; m < 4; ++m) {
        int e = (m * 256 + (int)threadIdx.x) * 4;
        if (e + 3 < len) {
            int4 w4 = *(const int4*)(cpack + base + e);
            atomicAdd(&cnt[w4.x >> 17], 1);
            atomicAdd(&cnt[w4.y >> 17], 1);
            atomicAdd(&cnt[w4.z >> 17], 1);
            atomicAdd(&cnt[w4.w >> 17], 1);
        } else {
            for (int ee = e; ee < len && ee >= 0; ++ee)
                atomicAdd(&cnt[cpack[base + ee] >> 17], 1);
        }
    }
    __syncthreads();
    int* row = partialD + (size_t)c * SBN;
    for (int i = threadIdx.x; i < SBN; i += 256) row[i] = cnt[i];
}

// ---- K5 reduceDeg: per-node degree -> degf, dinv, sxw -----------------------
__global__ __launch_bounds__(256) void reduceDeg_kernel(
    const int* __restrict__ partialD, const int* __restrict__ sbT,
    const float* __restrict__ xw,
    float* __restrict__ degf, float* __restrict__ dinv, float* __restrict__ sxw,
    int n_nodes, int ns)
{
    __shared__ int sbsL[NSMAX + 1], cstL[NSMAX + 1];
    build_tables(sbT, ns, sbsL, cstL);
    __syncthreads();
    int i = blockIdx.x * 256 + threadIdx.x;
    if (i >= n_nodes) return;
    int sb = i >> SBSHIFT, li = i & (SBN - 1);
    int c0 = cstL[sb], c1 = cstL[sb + 1];
    int d = 0;
    for (int c = c0; c < c1; ++c) d += partialD[(size_t)c * SBN + li];
    float df = (float)d;
    degf[i] = df;
    float di = rsqrtf(df + 1.0f);        // GCN degree includes self-loop
    dinv[i] = di;
    sxw[i]  = di * xw[i];
}

// ---- K6 chunkAcc: per output chunk, sum of sxw[src] -> dense partial row ----
__global__ __launch_bounds__(256) void chunkAcc_kernel(
    const int* __restrict__ cpack, const int* __restrict__ sbT,
    const float* __restrict__ sxw, float* __restrict__ partialF, int ns)
{
    __shared__ int sbsL[NSMAX + 1], cstL[NSMAX + 1];
    __shared__ float facc[SBN];
    build_tables(sbT, ns, sbsL, cstL);
    for (int i = threadIdx.x; i < SBN; i += 256) facc[i] = 0.0f;
    __syncthreads();
    int c = blockIdx.x;
    if (c >= cstL[ns]) return;
    int lo = 0, hi = ns;
    while (hi - lo > 1) { int mid = (lo + hi) >> 1; if (cstL[mid] <= c) lo = mid; else hi = mid; }
    int sb = lo;
    int i0 = c - cstL[sb];
    int base = sbsL[sb] + i0 * CH;
    int len = sbsL[sb + 1] - base; if (len > CH) len = CH;

    #pragma unroll
    for (int m = 0; m < 4; ++m) {
        int e = (m * 256 + (int)threadIdx.x) * 4;
        if (e + 3 < len) {
            int4 w4 = *(const int4*)(cpack + base + e);
            atomicAdd(&facc[w4.x >> 17], sxw[w4.x & 0x1FFFF]);
            atomicAdd(&facc[w4.y >> 17], sxw[w4.y & 0x1FFFF]);
            atomicAdd(&facc[w4.z >> 17], sxw[w4.z & 0x1FFFF]);
            atomicAdd(&facc[w4.w >> 17], sxw[w4.w & 0x1FFFF]);
        } else {
            for (int ee = e; ee < len && ee >= 0; ++ee) {
                int w = cpack[base + ee];
                atomicAdd(&facc[w >> 17], sxw[w & 0x1FFFF]);
            }
        }
    }
    __syncthreads();
    float* row = partialF + (size_t)c * SBN;
    for (int i = threadIdx.x; i < SBN; i += 256) row[i] = facc[i];
}

// ---- K7 reduceFinal: per-node accumulate + fused epilogue -------------------
__global__ __launch_bounds__(256) void reduceFinal_kernel(
    const float* __restrict__ partialF, const int* __restrict__ sbT,
    const float* __restrict__ degf, const float* __restrict__ dinv,
    const float* __restrict__ xw, const float* __restrict__ s2dot,
    const float* __restrict__ s3lin,
    const float* __restrict__ alpha, const float* __restrict__ beta,
    const float* __restrict__ Watt, const float* __restrict__ batt,
    float* __restrict__ out, int n_nodes, int ns)
{
    __shared__ int sbsL[NSMAX + 1], cstL[NSMAX + 1];
    build_tables(sbT, ns, sbsL, cstL);
    __syncthreads();
    int i = blockIdx.x * 256 + threadIdx.x;
    if (i >= n_nodes) return;
    int sb = i >> SBSHIFT, li = i & (SBN - 1);
    int c0 = cstL[sb], c1 = cstL[sb + 1];
    float acc = 0.0f;
    for (int c = c0; c < c1; ++c) acc += partialF[(size_t)c * SBN + li];

    float dn = dinv[i];
    float g  = acc * dn + dn * dn * xw[i];     // factored norm + self-loop
    float s1 = sigmoidf_(alpha[0] * sqrtf(degf[i]) + beta[0]);
    float s2 = sigmoidf_(s2dot[i]);
    float s3 = sigmoidf_(g + s3lin[i]);

    float z0 = Watt[0]*s1 + Watt[1]*s2 + Watt[2]*s3 + batt[0];
    float z1 = Watt[3]*s1 + Watt[4]*s2 + Watt[5]*s3 + batt[1];
    float z2 = Watt[6]*s1 + Watt[7]*s2 + Watt[8]*s3 + batt[2];

    float m  = fmaxf(z0, fmaxf(z1, z2));
    float e0 = expf(z0 - m), e1 = expf(z1 - m), e2 = expf(z2 - m);
    float inv = 1.0f / (e0 + e1 + e2);
    out[i] = (e0 * s1 + e1 * s2 + e2 * s3) * inv;
}

extern "C" void kernel_launch(void* const* d_in, const int* in_sizes, int n_in,
                              void* d_out, int out_size, void* d_ws, size_t ws_size,
                              hipStream_t stream) {
    const float* x     = (const float*)d_in[0];
    const int*   ei    = (const int*)d_in[1];
    const float* alpha = (const float*)d_in[2];
    const float* beta  = (const float*)d_in[3];
    const float* Wmlp  = (const float*)d_in[4];
    const float* Wlin  = (const float*)d_in[5];
    const float* Wgcn  = (const float*)d_in[6];
    const float* Watt  = (const float*)d_in[7];
    const float* batt  = (const float*)d_in[8];
    float* out = (float*)d_out;

    int n_nodes = in_sizes[0] / N_CH;
    int n_edges = in_sizes[1] / 2;
    const int* src = ei;
    const int* dst = ei + n_edges;

    int ns  = (n_nodes + SBN - 1) >> SBSHIFT;        // 49
    int nch = (n_edges + CH - 1) / CH;               // 782
    int maxChunks = nch + ns;                        // 831 (output chunk bound)

    // ws layout (4-byte elements, 1024-aligned regions)
    size_t off = 0;
    int*   cpack    = (int*)d_ws;          off += (((size_t)n_edges + 1023) & ~(size_t)1023);
    int*   H1       = (int*)d_ws + off;    off += (((size_t)ns * nch + 1023) & ~(size_t)1023);
    int*   O        = (int*)d_ws + off;    off += (((size_t)ns * nch + 1023) & ~(size_t)1023);
    int*   sbT      = (int*)d_ws + off;    off += 128;
    int*   partialD = (int*)d_ws + off;    off += (size_t)maxChunks * SBN;
    float* partialF = (float*)d_ws + off;  off += (size_t)maxChunks * SBN;
    float* s2dot    = (float*)d_ws + off;  off += (((size_t)n_nodes + 1023) & ~(size_t)1023);
    float* s3lin    = (float*)d_ws + off;  off += (((size_t)n_nodes + 1023) & ~(size_t)1023);
    float* xw       = (float*)d_ws + off;  off += (((size_t)n_nodes + 1023) & ~(size_t)1023);
    float* degf     = (float*)d_ws + off;  off += (((size_t)n_nodes + 1023) & ~(size_t)1023);
    float* dinv     = (float*)d_ws + off;  off += (((size_t)n_nodes + 1023) & ~(size_t)1023);
    float* sxw      = (float*)d_ws + off;  off += (((size_t)n_nodes + 1023) & ~(size_t)1023);

    int dotsBlocks = (n_nodes + 3) / 4;
    dots_hist_kernel<<<nch + dotsBlocks, 256, 0, stream>>>(
        x, Wmlp, Wlin, Wgcn, dst, s2dot, s3lin, xw, H1,
        n_nodes, n_edges, ns, nch);

    scanA_kernel<<<ns, 1024, 0, stream>>>(H1, O, sbT, nch);

    scatter_kernel<<<nch, 256, 0, stream>>>(src, dst, sbT, O, cpack,
                                            n_edges, ns, nch);

    chunkDeg_kernel<<<maxChunks, 256, 0, stream>>>(cpack, sbT, partialD, ns);

    reduceDeg_kernel<<<(n_nodes + 255) / 256, 256, 0, stream>>>(
        partialD, sbT, xw, degf, dinv, sxw, n_nodes, ns);

    chunkAcc_kernel<<<maxChunks, 256, 0, stream>>>(cpack, sbT, sxw, partialF, ns);

    reduceFinal_kernel<<<(n_nodes + 255) / 256, 256, 0, stream>>>(
        partialF, sbT, degf, dinv, xw, s2dot, s3lin,
        alpha, beta, Watt, batt, out, n_nodes, ns);
}